// Round 14
// baseline (191.959 us; speedup 1.0000x reference)
//
#include <hip/hip_runtime.h>
#include <type_traits>

#define BATCH 2
#define S_LEN 2048
#define DIM 2048
#define NH 16
#define NKV 4
#define HD 128

typedef _Float16 f16x8 __attribute__((ext_vector_type(8)));
typedef float f32x4 __attribute__((ext_vector_type(4)));
typedef unsigned int u32x4 __attribute__((ext_vector_type(4)));
typedef unsigned short u16x4 __attribute__((ext_vector_type(4)));
typedef unsigned short u16x8 __attribute__((ext_vector_type(8)));

__device__ __forceinline__ unsigned short f2h_bits(float f) {
  _Float16 h = (_Float16)f;
  return __builtin_bit_cast(unsigned short, h);
}
__device__ __forceinline__ float h2f(unsigned short u) {
  return (float)__builtin_bit_cast(_Float16, u);
}
__device__ __forceinline__ f16x8 ld8(const unsigned short* p) {
  u32x4 v = *reinterpret_cast<const u32x4*>(p);
  return __builtin_bit_cast(f16x8, v);
}
__device__ __forceinline__ void gload_lds16(const unsigned short* g, unsigned short* l) {
  __builtin_amdgcn_global_load_lds(
      (const __attribute__((address_space(1))) unsigned int*)g,
      (__attribute__((address_space(3))) unsigned int*)l, 16, 0, 0);
}

#define VMWAIT(n) asm volatile("s_waitcnt vmcnt(" #n ")" ::: "memory")

// ---------------- fused fp32 -> fp16 convert ----------------
__global__ __launch_bounds__(256) void cvt_all(const float* __restrict__ x,
                                               const float* __restrict__ Wq,
                                               const float* __restrict__ Wk,
                                               const float* __restrict__ Wv,
                                               const float* __restrict__ Wp,
                                               unsigned short* __restrict__ xb,
                                               unsigned short* __restrict__ wqkv,
                                               unsigned short* __restrict__ wpj) {
  int i = blockIdx.x * 256 + threadIdx.x;
  const float* src;
  unsigned short* dst;
  if (i < 2097152) {
    src = x + (long)i * 4; dst = xb + (long)i * 4;
  } else if (i < 3145728) {
    int k = i - 2097152; src = Wq + (long)k * 4; dst = wqkv + (long)k * 4;
  } else if (i < 3407872) {
    int k = i - 3145728; src = Wk + (long)k * 4; dst = wqkv + 4194304 + (long)k * 4;
  } else if (i < 3670016) {
    int k = i - 3407872; src = Wv + (long)k * 4; dst = wqkv + 5242880 + (long)k * 4;
  } else {
    int k = i - 3670016; src = Wp + (long)k * 4; dst = wpj + (long)k * 4;
  }
  f32x4 v = *reinterpret_cast<const f32x4*>(src);
  u16x4 o;
  o.x = f2h_bits(v.x); o.y = f2h_bits(v.y); o.z = f2h_bits(v.z); o.w = f2h_bits(v.w);
  *reinterpret_cast<u16x4*>(dst) = o;
}

// ---------------- RoPE tables (fp32) ----------------
__global__ __launch_bounds__(256) void rope_tables(float* __restrict__ c, float* __restrict__ s) {
  int idx = blockIdx.x * 256 + threadIdx.x;
  if (idx >= S_LEN * 16) return;
  int i = idx & 15, t = idx >> 4;
  float inv = exp2f(-(float)i * (13.287712379549449f / 16.0f));
  float f = (float)t * inv;
  c[idx] = cosf(f);
  s[idx] = sinf(f);
}

// ======== fused qkv GEMM: 128x128 tiles (1 head per col-tile), BK=32, 4 slots,
// counted vmcnt 2-ahead; epilogue = RMSNorm + RoPE + gain -> Qb/Kb, V -> Vt transpose ========
// Grid (32, 24): by 0-15 Q-head by | 16-19 K-head by-16 | 20-23 V-head by-20.
// 256 thr = 4 waves (wm = wid>>1, wn = wid&1); per-wave out 64x64 (4x4 frags).
__global__ __launch_bounds__(256, 2) void gemm_qkv(const unsigned short* __restrict__ A,
                                                   const unsigned short* __restrict__ B,
                                                   const float* __restrict__ ctab,
                                                   const float* __restrict__ stab,
                                                   const float* __restrict__ qgain,
                                                   unsigned short* __restrict__ Qb,
                                                   unsigned short* __restrict__ Kb,
                                                   unsigned short* __restrict__ Vt) {
  __shared__ unsigned short lds[4][8192];  // slot: A[128][32] at 0, B[128][32] at 4096
  const int tid = threadIdx.x, lane = tid & 63;
  const int wm = (tid >> 7) & 1, wn = (tid >> 6) & 1;
  const int rlo = lane & 15, hi = lane >> 4;
  const int m0 = blockIdx.x * 128;
  const int by = blockIdx.y;
  const int n0 = by * 128;
  const int K = 2048, NT = 64;

  const int i0 = tid, i1 = tid + 256;
  const int ar0 = i0 >> 2, ar1 = i1 >> 2;
  const unsigned short* pA0 = A + (long)(m0 + ar0) * K + (((i0 & 3) ^ ((ar0 >> 1) & 3)) * 8);
  const unsigned short* pA1 = A + (long)(m0 + ar1) * K + (((i1 & 3) ^ ((ar1 >> 1) & 3)) * 8);
  const unsigned short* pB0 = B + (long)(n0 + ar0) * K + (((i0 & 3) ^ ((ar0 >> 1) & 3)) * 8);
  const unsigned short* pB1 = B + (long)(n0 + ar1) * K + (((i1 & 3) ^ ((ar1 >> 1) & 3)) * 8);

  auto stage = [&](int slot) {
    gload_lds16(pA0, &lds[slot][i0 * 8]);
    gload_lds16(pA1, &lds[slot][i1 * 8]);
    gload_lds16(pB0, &lds[slot][4096 + i0 * 8]);
    gload_lds16(pB1, &lds[slot][4096 + i1 * 8]);
    pA0 += 32; pA1 += 32; pB0 += 32; pB1 += 32;
  };

  f32x4 acc[4][4] = {};

  stage(0);
  stage(1);
  for (int t = 0; t < NT; ++t) {
    const int slot = t & 3;
    if (t == NT - 1) VMWAIT(0); else VMWAIT(4);
    __builtin_amdgcn_s_barrier();
    asm volatile("" ::: "memory");
    if (t + 2 < NT) stage((t + 2) & 3);
    const unsigned short* As = &lds[slot][0];
    const unsigned short* Bs = &lds[slot][4096];
    f16x8 af[4], bf[4];
#pragma unroll
    for (int j = 0; j < 4; ++j) {
      int r = wn * 64 + j * 16 + rlo;
      bf[j] = ld8(&Bs[r * 32 + ((hi ^ ((r >> 1) & 3)) * 8)]);
    }
#pragma unroll
    for (int i2 = 0; i2 < 4; ++i2) {
      int r = wm * 64 + i2 * 16 + rlo;
      af[i2] = ld8(&As[r * 32 + ((hi ^ ((r >> 1) & 3)) * 8)]);
    }
    __builtin_amdgcn_s_setprio(1);
#pragma unroll
    for (int i2 = 0; i2 < 4; ++i2)
#pragma unroll
      for (int j = 0; j < 4; ++j)
        acc[i2][j] = __builtin_amdgcn_mfma_f32_16x16x32_f16(af[i2], bf[j], acc[i2][j], 0, 0, 0);
    __builtin_amdgcn_s_setprio(0);
  }

  __syncthreads();  // all compute done; safe to reuse LDS
  if (by < 20) {
    // --- RMS row sums (row = wm*64 + ms*16 + hi*4 + rr; this wave holds 64 cols) ---
    float* fs = (float*)&lds[0][0];  // [wn][128] row partials
#pragma unroll
    for (int ms = 0; ms < 4; ++ms)
#pragma unroll
      for (int rr = 0; rr < 4; ++rr) {
        float p = acc[ms][0][rr] * acc[ms][0][rr] + acc[ms][1][rr] * acc[ms][1][rr] +
                  acc[ms][2][rr] * acc[ms][2][rr] + acc[ms][3][rr] * acc[ms][3][rr];
        p += __shfl_xor(p, 1); p += __shfl_xor(p, 2);
        p += __shfl_xor(p, 4); p += __shfl_xor(p, 8);
        if (rlo == ms * 4 + rr) fs[wn * 128 + wm * 64 + ms * 16 + hi * 4 + rr] = p;
      }
    __syncthreads();
    const bool isQ = by < 16;
    const int hh = isQ ? by : (by - 16);
    const float g = isQ ? qgain[hh] : 1.0f;
#pragma unroll
    for (int ms = 0; ms < 4; ++ms)
#pragma unroll
      for (int rr = 0; rr < 4; ++rr) {
        int rowb = wm * 64 + ms * 16 + hi * 4 + rr;
        int m = m0 + rowb;
        int b = m >> 11, s = m & (S_LEN - 1);
        float rs = fs[rowb] + fs[128 + rowb];
        float rn = rsqrtf(rs * (1.0f / 128.0f) + 1.1920929e-07f);
        float v0 = acc[ms][0][rr] * rn, v1 = acc[ms][1][rr] * rn;
        float v2 = acc[ms][2][rr] * rn, v3 = acc[ms][3][rr] * rn;
        if (wn == 0) {  // cols 0..31 = rotary region; pairs (d, d+16) = (j0, j1) same lane
          float c = ctab[s * 16 + rlo], sn = stab[s * 16 + rlo];
          float a0 = v0, a1 = v1;
          v0 = a0 * c + a1 * sn;
          v1 = -a0 * sn + a1 * c;
        }
        unsigned short* dst = (isQ ? Qb + (((long)(b * NH + hh)) * S_LEN + s) * HD
                                   : Kb + (((long)(b * NKV + hh)) * S_LEN + s) * HD) +
                              wn * 64 + rlo;
        dst[0]  = f2h_bits(v0 * g);
        dst[16] = f2h_bits(v1 * g);
        dst[32] = f2h_bits(v2 * g);
        dst[48] = f2h_bits(v3 * g);
      }
  } else {
    // --- V: no norm; write transposed into Vt[b][kvh][d][s] ---
    const int kvh = by - 20;
#pragma unroll
    for (int ms = 0; ms < 4; ++ms) {
      int m = m0 + wm * 64 + ms * 16 + hi * 4;
      int b = m >> 11, s = m & (S_LEN - 1);
#pragma unroll
      for (int j = 0; j < 4; ++j) {
        int d = wn * 64 + j * 16 + rlo;
        u16x4 o;
#pragma unroll
        for (int rr = 0; rr < 4; ++rr) o[rr] = f2h_bits(acc[ms][j][rr]);
        *reinterpret_cast<u16x4*>(Vt + (((long)(b * NKV + kvh)) * HD + d) * S_LEN + s) = o;
      }
    }
  }
}

// ======== GEMM: BK=32, 4 LDS slots, stage-2-ahead, counted vmcnt (round-11 proven) ========
template <int NREP, typename OUT>
__global__ __launch_bounds__(512, 2) void gemm_pl(const unsigned short* __restrict__ A,
                                                  const unsigned short* __restrict__ B,
                                                  OUT* __restrict__ C, int K, int ldc) {
  constexpr int BN = 64 * NREP;
  constexpr int BSH = BN * 32;
  constexpr int TS = 8192 + BSH;
  __shared__ unsigned short lds[4][TS];
  const int tid = threadIdx.x, lane = tid & 63;
  const int wm = tid >> 8, wn = (tid >> 6) & 3;
  const int rlo = lane & 15, hi = lane >> 4;
  const int m0 = blockIdx.x * 256, n0 = blockIdx.y * BN;
  const int NT = K >> 5;
  const int brow = wn * (16 * NREP);

  auto aRow = [&](int sig) { return (sig & 63) + ((sig >> 6) & 1) * 128 + (sig >> 7) * 64; };

  const int sigA0 = tid >> 2, sigA1 = 128 + (tid >> 2);
  const unsigned short* pA0 =
      A + (long)(m0 + aRow(sigA0)) * K + (((tid & 3) ^ ((sigA0 >> 1) & 3)) * 8);
  const unsigned short* pA1 =
      A + (long)(m0 + aRow(sigA1)) * K + (((tid & 3) ^ ((sigA1 >> 1) & 3)) * 8);
  const int rB0 = tid >> 2;
  const unsigned short* pB0 = B + (long)(n0 + rB0) * K + (((tid & 3) ^ ((rB0 >> 1) & 3)) * 8);
  const int idx1 = 512 + (tid & 255);
  const int rB1 = idx1 >> 2;
  const unsigned short* pB1 = B + (long)(n0 + rB1) * K + (((idx1 & 3) ^ ((rB1 >> 1) & 3)) * 8);

  auto stage = [&](int slot) {
    gload_lds16(pA0, &lds[slot][tid * 8]);
    gload_lds16(pA1, &lds[slot][4096 + tid * 8]);
    gload_lds16(pB0, &lds[slot][8192 + tid * 8]);
    if constexpr (NREP == 3) gload_lds16(pB1, &lds[slot][8192 + idx1 * 8]);
    pA0 += 32; pA1 += 32; pB0 += 32;
    if constexpr (NREP == 3) pB1 += 32;
  };

  f32x4 acc[8][NREP] = {};

  auto rdA = [&](const unsigned short* As, int mh, f16x8* af) {
#pragma unroll
    for (int i = 0; i < 4; ++i) {
      int ms = mh * 4 + i;
      int sig = (ms & 3) * 16 + rlo + wm * 64 + (ms >> 2) * 128;
      af[i] = ld8(&As[sig * 32 + ((hi ^ ((sig >> 1) & 3)) * 8)]);
    }
  };
  auto rdB = [&](const unsigned short* Bs, f16x8* bf) {
#pragma unroll
    for (int j = 0; j < NREP; ++j) {
      int r = brow + j * 16 + rlo;
      bf[j] = ld8(&Bs[r * 32 + ((hi ^ ((r >> 1) & 3)) * 8)]);
    }
  };
  auto mm = [&](const f16x8* af, const f16x8* bf, int mh) {
    __builtin_amdgcn_s_setprio(1);
#pragma unroll
    for (int i = 0; i < 4; ++i)
#pragma unroll
      for (int j = 0; j < NREP; ++j)
        acc[mh * 4 + i][j] =
            __builtin_amdgcn_mfma_f32_16x16x32_f16(af[i], bf[j], acc[mh * 4 + i][j], 0, 0, 0);
    __builtin_amdgcn_s_setprio(0);
  };

  stage(0);
  stage(1);
  for (int t = 0; t < NT; ++t) {
    const int slot = t & 3;
    if (t == NT - 1) {
      VMWAIT(0);
    } else {
      if constexpr (NREP == 3) VMWAIT(4); else VMWAIT(3);
    }
    __builtin_amdgcn_s_barrier();
    asm volatile("" ::: "memory");
    if (t + 2 < NT) stage((t + 2) & 3);
    const unsigned short* As = &lds[slot][0];
    const unsigned short* Bs = &lds[slot][8192];
    f16x8 bf[NREP], af0[4], af1[4];
    rdB(Bs, bf);
    rdA(As, 0, af0);
    rdA(As, 1, af1);
    mm(af0, bf, 0);
    mm(af1, bf, 1);
  }

#pragma unroll
  for (int ms = 0; ms < 8; ++ms)
#pragma unroll
    for (int j = 0; j < NREP; ++j) {
      int row = m0 + wm * 128 + ms * 16 + hi * 4;
      int col = n0 + brow + j * 16 + rlo;
#pragma unroll
      for (int r = 0; r < 4; ++r) {
        float v = acc[ms][j][r];
        if constexpr (std::is_same<OUT, float>::value)
          C[(long)(row + r) * ldc + col] = v;
        else
          C[(long)(row + r) * ldc + col] = f2h_bits(v);
      }
    }
}

// ======== causal GQA attention (round-11 proven: heavy-first quarters, invariant addr) ========
#define ATT_C3 ((float)(0.08838834764831845 * (2.0 / 30.0) * 1.4426950408889634))
#define ATT_C4 ((float)(30.0 * 1.4426950408889634))
#define ATT_C5 ((float)(60.0 * 1.4426950408889634))
#define ATT_THR ((float)(8.0 * 1.4426950408889634))

__global__ __launch_bounds__(256, 4) void attn(const unsigned short* __restrict__ Qb,
                                               const unsigned short* __restrict__ Kb,
                                               const unsigned short* __restrict__ Vt,
                                               unsigned short* __restrict__ Yb) {
  __shared__ unsigned short sm[2][8192];
  const int tid = threadIdx.x, wid = tid >> 6, lane = tid & 63;
  const int gx = blockIdx.x;
  const int qq = gx >> 8;
  const int a = (gx >> 5) & 7;
  const int h = gx & 15, b = (gx >> 4) & 1;
  int qb;
  if (qq == 0) qb = 31 - a;
  else if (qq == 1) qb = 16 + a;
  else if (qq == 2) qb = 15 - a;
  else qb = a;

  const int kvh = h >> 2;
  const int rlo = lane & 15, hi = lane >> 4;
  const int q0 = qb * 64 + wid * 16;
  const unsigned short* Kp = Kb + ((long)(b * NKV + kvh)) * S_LEN * HD;
  const unsigned short* Vp = Vt + ((long)(b * NKV + kvh)) * HD * S_LEN;
  const unsigned short* Qp = Qb + (((long)(b * NH + h)) * S_LEN + q0) * HD;
  f16x8 bq[4];
#pragma unroll
  for (int dk = 0; dk < 4; ++dk) bq[dk] = ld8(Qp + rlo * HD + dk * 32 + hi * 8);

  const int kx = rlo & 7;
  const int vx = hi ^ ((rlo >> 1) & 3);
  const unsigned short* aK[4];
#pragma unroll
  for (int dk = 0; dk < 4; ++dk) aK[dk] = &sm[0][rlo * 128 + ((dk * 4 + hi) ^ kx) * 8];
  const unsigned short* aV = &sm[0][4096 + rlo * 32 + vx * 8];

  const int i0 = tid, i1 = tid + 256;
  const int rho0 = i0 >> 4, rho1 = i1 >> 4;
  auto kvperm = [](int r) { return 8 * ((r >> 2) & 3) + (r & 3) + 4 * (r >> 4); };
  const unsigned short* sK0 = Kp + (long)kvperm(rho0) * HD + ((i0 & 15) ^ (rho0 & 7)) * 8;
  const unsigned short* sK1 = Kp + (long)kvperm(rho1) * HD + ((i1 & 15) ^ (rho1 & 7)) * 8;
  const int vd0 = i0 >> 2, vd1 = i1 >> 2;
  const unsigned short* sV0 = Vp + (long)vd0 * S_LEN + ((i0 & 3) ^ ((vd0 >> 1) & 3)) * 8;
  const unsigned short* sV1 = Vp + (long)vd1 * S_LEN + ((i1 & 3) ^ ((vd1 >> 1) & 3)) * 8;
  unsigned short* dK0 = &sm[0][rho0 * 128 + (i0 & 15) * 8];
  unsigned short* dK1 = &sm[0][rho1 * 128 + (i1 & 15) * 8];
  unsigned short* dV0 = &sm[0][4096 + vd0 * 32 + (i0 & 3) * 8];
  unsigned short* dV1 = &sm[0][4096 + vd1 * 32 + (i1 & 3) * 8];

  f32x4 acc[8] = {};
  float m2c = ATT_C4 + 128.0f;
  float l_run = 0.0f;
  const int nt = 2 * qb + 2;
  const int twlast = 2 * qb + (wid >> 1);

#define STAGE(SLOT)                                                       \
  {                                                                       \
    gload_lds16(sK0, dK0 + (SLOT)*8192);                                  \
    gload_lds16(sK1, dK1 + (SLOT)*8192);                                  \
    gload_lds16(sV0, dV0 + (SLOT)*8192);                                  \
    gload_lds16(sV1, dV1 + (SLOT)*8192);                                  \
    sK0 += 4096; sK1 += 4096; sV0 += 32; sV1 += 32;                       \
  }

#define COMPUTE(T, SLOT)                                                              \
  {                                                                                   \
    f16x8 ka0[4], ka1[4];                                                             \
    _Pragma("unroll")                                                                 \
    for (int dk = 0; dk < 4; ++dk) {                                                  \
      ka0[dk] = ld8(aK[dk] + (SLOT)*8192);                                            \
      ka1[dk] = ld8(aK[dk] + (SLOT)*8192 + 2048);                                     \
    }                                                                                 \
    f32x4 s0 = {0.f, 0.f, 0.f, 0.f}, s1 = s0;                                         \
    __builtin_amdgcn_s_setprio(1);                                                    \
    _Pragma("unroll")                                                                 \
    for (int dk = 0; dk < 4; ++dk) {                                                  \
      s0 = __builtin_amdgcn_mfma_f32_16x16x32_f16(ka0[dk], bq[dk], s0, 0, 0, 0);      \
      s1 = __builtin_amdgcn_mfma_f32_16x16x32_f16(ka1[dk], bq[dk], s1, 0, 0, 0);      \
    }                                                                                 \
    __builtin_amdgcn_s_setprio(0);                                                    \
    float ea[8];                                                                      \
    _Pragma("unroll")                                                                 \
    for (int jj = 0; jj < 8; ++jj) {                                                  \
      float sc = (jj < 4) ? s0[jj] : s1[jj - 4];                                      \
      float u = __builtin_amdgcn_exp2f(sc * ATT_C3);                                  \
      float rr = __builtin_amdgcn_rcpf(u + 1.0f);                                     \
      ea[jj] = fmaf(-ATT_C5, rr, m2c);                                                \
    }                                                                                 \
    if ((T) == twlast) {                                                              \
      int qrel = q0 + rlo - 32 * (T);                                                 \
      _Pragma("unroll")                                                               \
      for (int jj = 0; jj < 8; ++jj)                                                  \
        ea[jj] = (8 * hi + jj > qrel) ? -1e30f : ea[jj];                              \
    }                                                                                 \
    float pm = ea[0];                                                                 \
    _Pragma("unroll")                                                                 \
    for (int jj = 1; jj < 8; ++jj) pm = fmaxf(pm, ea[jj]);                            \
    if (!__all(pm <= ATT_THR)) {                                                      \
      float red = fmaxf(pm, __shfl_xor(pm, 16));                                      \
      red = fmaxf(red, __shfl_xor(red, 32));                                          \
      red = fmaxf(red, 0.0f);                                                         \
      m2c -= red;                                                                     \
      float ff = __builtin_amdgcn_exp2f(-red);                                        \
      l_run *= ff;                                                                    \
      _Pragma("unroll")                                                               \
      for (int dt = 0; dt < 8; ++dt) acc[dt] *= ff;                                   \
      _Pragma("unroll")                                                               \
      for (int jj = 0; jj < 8; ++jj) ea[jj] -= red;                                   \
    }                                                                                 \
    float pv[8];                                                                      \
    _Pragma("unroll")                                                                 \
    for (int jj = 0; jj < 8; ++jj) pv[jj] = __builtin_amdgcn_exp2f(ea[jj]);           \
    l_run += ((pv[0] + pv[1]) + (pv[2] + pv[3])) + ((pv[4] + pv[5]) + (pv[6] + pv[7]));\
    u32x4 pk;                                                                         \
    pk.x = __builtin_bit_cast(unsigned int, __builtin_amdgcn_cvt_pkrtz(pv[0], pv[1]));\
    pk.y = __builtin_bit_cast(unsigned int, __builtin_amdgcn_cvt_pkrtz(pv[2], pv[3]));\
    pk.z = __builtin_bit_cast(unsigned int, __builtin_amdgcn_cvt_pkrtz(pv[4], pv[5]));\
    pk.w = __builtin_bit_cast(unsigned int, __builtin_amdgcn_cvt_pkrtz(pv[6], pv[7]));\
    f16x8 bp = __builtin_bit_cast(f16x8, pk);                                         \
    __builtin_amdgcn_s_setprio(1);                                                    \
    _Pragma("unroll")                                                                 \
    for (int g = 0; g < 2; ++g) {                                                     \
      f16x8 av[4];                                                                    \
      _Pragma("unroll")                                                               \
      for (int i = 0; i < 4; ++i) av[i] = ld8(aV + (SLOT)*8192 + (g * 4 + i) * 512);  \
      _Pragma("unroll")                                                               \
      for (int i = 0; i < 4; ++i)                                                     \
        acc[g * 4 + i] =                                                              \
            __builtin_amdgcn_mfma_f32_16x16x32_f16(av[i], bp, acc[g * 4 + i], 0, 0, 0);\
    }                                                                                 \
    __builtin_amdgcn_s_setprio(0);                                                    \
  }

  STAGE(0);
  for (int t = 0; t < nt; t += 2) {
    VMWAIT(0);
    __builtin_amdgcn_s_barrier();
    asm volatile("" ::: "memory");
    STAGE(1);
    if (t <= twlast) COMPUTE(t, 0);
    VMWAIT(0);
    __builtin_amdgcn_s_barrier();
    asm volatile("" ::: "memory");
    if (t + 2 < nt) STAGE(0);
    if (t + 1 <= twlast) COMPUTE(t + 1, 1);
  }
#undef STAGE
#undef COMPUTE

  float l = l_run + __shfl_xor(l_run, 16);
  l += __shfl_xor(l, 32);
  float inv = 1.0f / l;
  unsigned short* yp = Yb + ((long)(b * S_LEN + q0 + rlo)) * DIM + h * HD + 4 * hi;
#pragma unroll
  for (int dt = 0; dt < 8; ++dt) {
    u16x4 o;
#pragma unroll
    for (int r = 0; r < 4; ++r) o[r] = f2h_bits(acc[dt][r] * inv);
    *reinterpret_cast<u16x4*>(yp + dt * 16) = o;
  }
}

extern "C" void kernel_launch(void* const* d_in, const int* in_sizes, int n_in,
                              void* d_out, int out_size, void* d_ws, size_t ws_size,
                              hipStream_t stream) {
  const float* x = (const float*)d_in[0];
  const float* Wq = (const float*)d_in[1];
  const float* Wk = (const float*)d_in[2];
  const float* Wv = (const float*)d_in[3];
  const float* Wp = (const float*)d_in[4];
  const float* qg = (const float*)d_in[5];
  float* out = (float*)d_out;

  char* ws = (char*)d_ws;
  size_t off = 0;
  auto alloc = [&](size_t bytes) {
    char* p = ws + off;
    off += (bytes + 255) & ~(size_t)255;
    return p;
  };
  unsigned short* xb   = (unsigned short*)alloc(8388608ull * 2);
  unsigned short* wqkv = (unsigned short*)alloc(6291456ull * 2);
  unsigned short* wpj  = (unsigned short*)alloc(4194304ull * 2);
  unsigned short* Qbuf = (unsigned short*)alloc(8388608ull * 2);
  unsigned short* Kb   = (unsigned short*)alloc(2097152ull * 2);
  unsigned short* Vt   = (unsigned short*)alloc(2097152ull * 2);
  unsigned short* Yb   = (unsigned short*)alloc(8388608ull * 2);
  float* ctab = (float*)alloc(32768ull * 4);
  float* stab = (float*)alloc(32768ull * 4);

  cvt_all<<<18432, 256, 0, stream>>>(x, Wq, Wk, Wv, Wp, xb, wqkv, wpj);
  rope_tables<<<128, 256, 0, stream>>>(ctab, stab);

  // fused qkv projection + RMSNorm + RoPE + gain + V-transpose
  gemm_qkv<<<dim3(32, 24), 256, 0, stream>>>(xb, wqkv, ctab, stab, qg, Qbuf, Kb, Vt);

  attn<<<1024, 256, 0, stream>>>(Qbuf, Kb, Vt, Yb);

  // out = y @ Wproj^T : M=4096 N=2048 K=2048  (256x128 tiles -> 256 blocks)
  gemm_pl<2, float><<<dim3(16, 16), 512, 0, stream>>>(Yb, wpj, out, 2048, 2048);
}